// Round 14
// baseline (3441.244 us; speedup 1.0000x reference)
//
#include <hip/hip_runtime.h>

// R14: R13 + T5 (s_setprio around MFMA clusters). R13's stagger created the
// wave role-split (MFMA-phase wave vs VALU-phase wave per SIMD) that is T5's
// prerequisite; this round isolates whether issue arbitration is a lever or
// whether the per-SIMD MFMA/VALU additivity (R13 counters: 42%+61%~=103%)
// is a hard issue-block property. Everything else identical to R13 (3359us).

typedef short bf16x8 __attribute__((ext_vector_type(8)));
typedef float f32x4 __attribute__((ext_vector_type(4)));
typedef unsigned long long ull;

static constexpr int CIN = 12, T = 2048, H = 128;
static constexpr int NTHR = 512;
static constexpr float L2E = 1.4426950408889634f;

// LDS map
static constexpr int LW1 = 0;         // 131072  Wih1 frag image (pre-scaled bf16)
static constexpr int LH0 = 131072;    // 2 x 4096  h0 dbuf (B-frag image)
static constexpr int LH1 = 139264;    // 2 x 4096  h1 dbuf
static constexpr int LX  = 147456;    // 2 x 1024  x dbuf (k=12 col = 1.0 -> L0 bias)
static constexpr int LRED= 149504;    // 2048      epilogue reduction
static constexpr int LDS_SZ = 151552; // 148 KB

#if __has_builtin(__builtin_amdgcn_exp2f)
#define EXP2(x) __builtin_amdgcn_exp2f(x)
#else
#define EXP2(x) exp2f(x)
#endif

__device__ __forceinline__ unsigned f2bf(float f) {  // f32 -> bf16 bits, RTNE
  unsigned u = __builtin_bit_cast(unsigned, f);
  return (u + 0x7FFFu + ((u >> 16) & 1u)) >> 16;
}

__device__ __forceinline__ unsigned cvtpk_bf16(float lo, float hi) {
  unsigned r;
  asm("v_cvt_pk_bf16_f32 %0, %1, %2" : "=v"(r) : "v"(lo), "v"(hi));
  return r;
}

__device__ __forceinline__ float sig_pre(float a) {  // 1/(1+2^a)
  return __builtin_amdgcn_rcpf(1.f + EXP2(a));
}

__global__ __launch_bounds__(NTHR, 2) void lstm_merged(
    const float* __restrict__ xg,
    const float* __restrict__ Wih0, const float* __restrict__ Whh0,
    const float* __restrict__ bih0, const float* __restrict__ bhh0,
    const float* __restrict__ Wih1, const float* __restrict__ Whh1,
    const float* __restrict__ bih1, const float* __restrict__ bhh1,
    const float* __restrict__ Wd,   const float* __restrict__ bd,
    float* __restrict__ out)
{
  __shared__ char lds[LDS_SZ];
  const int tid = threadIdx.x;
  const int l  = tid & 63;
  const int w  = tid >> 6;   // wave 0..7
  const int lg = l >> 4;     // lane k-group 0..3
  const int lr = l & 15;     // A: row-in-tile ; B/D: batch column
  const int b0 = blockIdx.x * 16;
  const bool early = (w < 4);  // phase order group (SIMD i hosts waves i, i+4)

  // ---- zero h/x state region (LH0..LX end = 18432 B) ----
  for (int i = tid; i < 18432 / 4; i += NTHR) ((int*)(lds + LH0))[i] = 0;
  // ---- stage Wih1 -> LDS frag image (pre-scaled bf16), coalesced [R9-verified] ----
  {
    const float4* Wv = (const float4*)Wih1;   // 16384 float4s
    #pragma unroll 4
    for (int i = 0; i < 32; ++i) {
      const int idx = i * 512 + tid;          // float4 index
      const float4 f = Wv[idx];
      const int e0 = idx * 4;                 // element index
      const int n = e0 >> 7, k = e0 & 127;    // row 0..511, col (mult of 4)
      const int tau = n >> 4;
      const float s = ((tau >> 3) == 2) ? (2.f * L2E) : (-L2E);
      const int lane = ((k >> 3) & 3) * 16 + (n & 15);
      const int byte = ((tau * 4 + (k >> 5)) * 64 + lane) * 16 + (k & 7) * 2;
      const unsigned lo = cvtpk_bf16(f.x * s, f.y * s);
      const unsigned hi = cvtpk_bf16(f.z * s, f.w * s);
      *(ull*)(lds + LW1 + byte) = ((ull)hi << 32) | lo;   // 8B, 8-aligned
    }
  }
  __syncthreads();
  // const-1.0 column at k==12 of both X buffers (pairs with L0 bias column)
  if (tid < 32) {
    const int buf = tid >> 4, b = tid & 15;
    *(unsigned short*)(lds + LX + buf * 1024 + 256 + b * 16 + 8) = 0x3F80;
  }

  // ---- weight registers: A0 (Whh0 + x/bias kfrag), A1h (Whh1), b1r (L1 bias) ----
  bf16x8 A0[4][5];
  bf16x8 A1h[4][4];
  f32x4 b1r[4];
  #pragma unroll
  for (int q = 0; q < 4; ++q) {
    const int n = (q * 8 + w) * 16 + lr;         // global gate row
    const float s = (q == 2) ? (2.f * L2E) : (-L2E);
    #pragma unroll
    for (int kf = 0; kf < 4; ++kf) {
      const float* s0 = &Whh0[n * H + kf * 32 + lg * 8];
      const float* s1 = &Whh1[n * H + kf * 32 + lg * 8];
      #pragma unroll
      for (int j = 0; j < 8; ++j) {
        A0[q][kf][j]  = (short)f2bf(s0[j] * s);
        A1h[q][kf][j] = (short)f2bf(s1[j] * s);
      }
    }
    #pragma unroll
    for (int j = 0; j < 8; ++j) {
      const int k = lg * 8 + j;
      float v = 0.f;
      if (k < CIN) v = Wih0[n * CIN + k] * s;
      else if (k == CIN) v = (bih0[n] + bhh0[n]) * s;  // pairs with 1.0 in X
      A0[q][4][j] = (short)f2bf(v);
    }
    #pragma unroll
    for (int r = 0; r < 4; ++r) {
      const int nd = (q * 8 + w) * 16 + lg * 4 + r;   // D-frag row for this lane
      b1r[q][r] = (bih1[nd] + bhh1[nd]) * s;
    }
  }
  const f32x4 zed = {0.f, 0.f, 0.f, 0.f};

  // per-lane geometry
  const int rdB  = lg * 256 + lr * 16;                       // B-frag read base
  const int bcol = w * 16 + lg * 4;                          // base h-column
  const int wrH  = (bcol >> 3) * 256 + lr * 16 + (bcol & 7) * 2;
  const int xb = tid & 15, xc = tid >> 4;                    // x loader (tid<192)
  const int wrX = (xc >> 3) * 256 + xb * 16 + (xc & 7) * 2;
  const size_t xbase = (size_t)(b0 + xb) * (CIN * T) + (size_t)xc * T;

  if (tid < 192)
    *(unsigned short*)(lds + LX + wrX) = (unsigned short)f2bf(xg[xbase]);
  __syncthreads();

  float c0v[4] = {0.f, 0.f, 0.f, 0.f};
  float c1v[4] = {0.f, 0.f, 0.f, 0.f};
  float h1v[4] = {0.f, 0.f, 0.f, 0.f};

  // ---- phase lambdas (per-wave work identical; only ORDER differs) ----
  auto ph_accA = [&](const bf16x8 bfH0[4], const bf16x8& bfX, f32x4 accA[4]) {
    __builtin_amdgcn_s_setprio(1);                 // T5: favor MFMA-phase wave
    #pragma unroll
    for (int q = 0; q < 4; ++q)
      accA[q] = __builtin_amdgcn_mfma_f32_16x16x32_bf16(A0[q][4], bfX, zed, 0, 0, 0);
    #pragma unroll
    for (int kf = 0; kf < 4; ++kf)
      #pragma unroll
      for (int q = 0; q < 4; ++q)
        accA[q] = __builtin_amdgcn_mfma_f32_16x16x32_bf16(A0[q][kf], bfH0[kf], accA[q], 0, 0, 0);
    __builtin_amdgcn_s_setprio(0);
  };
  auto ph_ewL0 = [&](const f32x4 accA[4], int p) {
    float h0t[4];
    #pragma unroll
    for (int r = 0; r < 4; ++r) {
      const float iv = sig_pre(accA[0][r]);
      const float fv = sig_pre(accA[1][r]);
      const float gv = fmaf(-2.f, sig_pre(accA[2][r]), 1.f);
      const float ov = sig_pre(accA[3][r]);
      const float c  = fmaf(fv, c0v[r], iv * gv);
      c0v[r] = c;
      const float th = fmaf(-2.f, sig_pre(c * (2.f * L2E)), 1.f);
      h0t[r] = ov * th;
    }
    const unsigned hp0 = cvtpk_bf16(h0t[0], h0t[1]);
    const unsigned hp1 = cvtpk_bf16(h0t[2], h0t[3]);
    *(ull*)(lds + LH0 + p * 4096 + wrH) = ((ull)hp1 << 32) | hp0;
  };
  auto ph_accB = [&](const bf16x8 bfH0[4], const bf16x8 bfH1[4], f32x4 accB[4]) {
    __builtin_amdgcn_s_setprio(1);                 // T5
    #pragma unroll
    for (int q = 0; q < 4; ++q) accB[q] = b1r[q];
    #pragma unroll
    for (int kf = 0; kf < 4; ++kf) {
      bf16x8 af[4];                                          // Wih1 frags from LDS
      #pragma unroll
      for (int q = 0; q < 4; ++q)
        af[q] = *(const bf16x8*)(lds + LW1 + ((q * 8 + w) * 4 + kf) * 1024 + l * 16);
      #pragma unroll
      for (int q = 0; q < 4; ++q) {
        accB[q] = __builtin_amdgcn_mfma_f32_16x16x32_bf16(A1h[q][kf], bfH1[kf], accB[q], 0, 0, 0);
        accB[q] = __builtin_amdgcn_mfma_f32_16x16x32_bf16(af[q],      bfH0[kf], accB[q], 0, 0, 0);
      }
    }
    __builtin_amdgcn_s_setprio(0);
  };
  auto ph_ewL1 = [&](const f32x4 accB[4], int p) {
    #pragma unroll
    for (int r = 0; r < 4; ++r) {
      const float iv = sig_pre(accB[0][r]);
      const float fv = sig_pre(accB[1][r]);
      const float gv = fmaf(-2.f, sig_pre(accB[2][r]), 1.f);
      const float ov = sig_pre(accB[3][r]);
      const float c  = fmaf(fv, c1v[r], iv * gv);
      c1v[r] = c;
      const float th = fmaf(-2.f, sig_pre(c * (2.f * L2E)), 1.f);
      h1v[r] = ov * th;
    }
    const unsigned hp0 = cvtpk_bf16(h1v[0], h1v[1]);
    const unsigned hp1 = cvtpk_bf16(h1v[2], h1v[3]);
    *(ull*)(lds + LH1 + (1 - p) * 4096 + wrH) = ((ull)hp1 << 32) | hp0;
  };

  // Iter t: L0(t) (h0(t-1), x(t)) and L1(t-1) (h1(t-2), h0(t-1)).
  // read H0[1-p], H1[p], X[p]; write H0[p], H1[1-p], X[1-p]. One barrier.
  #pragma unroll 2
  for (int t = 0; t < T; ++t) {
    const int p = t & 1;
    float xnext = 0.f;
    if (tid < 192) xnext = xg[xbase + (t + 1 < T ? t + 1 : t)];

    bf16x8 bfH0[4], bfH1[4], bfX;
    #pragma unroll
    for (int kf = 0; kf < 4; ++kf) {
      bfH0[kf] = *(const bf16x8*)(lds + LH0 + (1 - p) * 4096 + kf * 1024 + rdB);
      bfH1[kf] = *(const bf16x8*)(lds + LH1 + p * 4096 + kf * 1024 + rdB);
    }
    bfX = *(const bf16x8*)(lds + LX + p * 1024 + rdB);

    f32x4 accA[4], accB[4];
    if (early) {
      ph_accA(bfH0, bfX, accA);
      ph_ewL0(accA, p);
      ph_accB(bfH0, bfH1, accB);
      if (t > 0) ph_ewL1(accB, p);
    } else {
      ph_accB(bfH0, bfH1, accB);
      if (t > 0) ph_ewL1(accB, p);
      ph_accA(bfH0, bfX, accA);
      ph_ewL0(accA, p);
    }

    if (tid < 192) {
      *(unsigned short*)(lds + LX + (1 - p) * 1024 + wrX) =
          (unsigned short)cvtpk_bf16(xnext, xnext);
    }
    __syncthreads();
  }

  // ---- peeled final L1 step: h1(T-1) <- h1(T-2), h0(T-1) ----
  // T even: h0(T-1) in H0[1], h1(T-2) in H1[0].
  {
    bf16x8 bfH0[4], bfH1[4];
    #pragma unroll
    for (int kf = 0; kf < 4; ++kf) {
      bfH0[kf] = *(const bf16x8*)(lds + LH0 + 4096 + kf * 1024 + rdB);
      bfH1[kf] = *(const bf16x8*)(lds + LH1 + kf * 1024 + rdB);
    }
    f32x4 accB[4];
    ph_accB(bfH0, bfH1, accB);
    #pragma unroll
    for (int r = 0; r < 4; ++r) {
      const float iv = sig_pre(accB[0][r]);
      const float fv = sig_pre(accB[1][r]);
      const float gv = fmaf(-2.f, sig_pre(accB[2][r]), 1.f);
      const float ov = sig_pre(accB[3][r]);
      const float c  = fmaf(fv, c1v[r], iv * gv);
      c1v[r] = c;
      const float th = fmaf(-2.f, sig_pre(c * (2.f * L2E)), 1.f);
      h1v[r] = ov * th;
    }
  }

  // ---- epilogue: feats = h1(T-1), scores = sigmoid(h1 . Wd + bd) ----
  const float4 wd = *(const float4*)&Wd[bcol];
  const float partial = h1v[0] * wd.x + h1v[1] * wd.y + h1v[2] * wd.z + h1v[3] * wd.w;
  #pragma unroll
  for (int r = 0; r < 4; ++r)
    out[256 + (size_t)(b0 + lr) * H + (bcol + r)] = h1v[r];
  ((float*)(lds + LRED))[tid] = partial;
  __syncthreads();
  if (tid < 16) {
    float s = 0.f;
    #pragma unroll 8
    for (int k = 0; k < 32; ++k) s += ((float*)(lds + LRED))[tid + 16 * k];
    const float v = s + bd[0];
    out[b0 + tid] = __builtin_amdgcn_rcpf(1.f + EXP2(-v * L2E));
  }
}

extern "C" void kernel_launch(void* const* d_in, const int* in_sizes, int n_in,
                              void* d_out, int out_size, void* d_ws, size_t ws_size,
                              hipStream_t stream) {
  const float* x    = (const float*)d_in[0];
  // d_in[1] = seq_lengths : unused by the reference
  const float* Wih0 = (const float*)d_in[2];
  const float* Whh0 = (const float*)d_in[3];
  const float* bih0 = (const float*)d_in[4];
  const float* bhh0 = (const float*)d_in[5];
  const float* Wih1 = (const float*)d_in[6];
  const float* Whh1 = (const float*)d_in[7];
  const float* bih1 = (const float*)d_in[8];
  const float* bhh1 = (const float*)d_in[9];
  const float* Wd   = (const float*)d_in[10];
  const float* bd   = (const float*)d_in[11];
  (void)in_sizes; (void)n_in; (void)out_size; (void)d_ws; (void)ws_size;

  lstm_merged<<<dim3(16), dim3(NTHR), 0, stream>>>(
      x, Wih0, Whh0, bih0, bhh0, Wih1, Whh1, bih1, bhh1, Wd, bd, (float*)d_out);
}

// Round 15
// 3356.527 us; speedup vs baseline: 1.0252x; 1.0252x over previous
//
#include <hip/hip_runtime.h>

// R15 == R13 (the measured optimum, 3359us): merged one-barrier fused LSTM
// with staggered per-wave-half phase order. R14's setprio (null, -2%) removed.
// Session evidence: this structure is within ~15% of the additive-issue floor
// (MFMA 2018 + trans ~640 + VALU + barrier/drain per step); all alternative
// topologies (cross-CU split, offload, wave crews) measured 1.5-4x worse.

typedef short bf16x8 __attribute__((ext_vector_type(8)));
typedef float f32x4 __attribute__((ext_vector_type(4)));
typedef unsigned long long ull;

static constexpr int CIN = 12, T = 2048, H = 128;
static constexpr int NTHR = 512;
static constexpr float L2E = 1.4426950408889634f;

// LDS map
static constexpr int LW1 = 0;         // 131072  Wih1 frag image (pre-scaled bf16)
static constexpr int LH0 = 131072;    // 2 x 4096  h0 dbuf (B-frag image)
static constexpr int LH1 = 139264;    // 2 x 4096  h1 dbuf
static constexpr int LX  = 147456;    // 2 x 1024  x dbuf (k=12 col = 1.0 -> L0 bias)
static constexpr int LRED= 149504;    // 2048      epilogue reduction
static constexpr int LDS_SZ = 151552; // 148 KB

#if __has_builtin(__builtin_amdgcn_exp2f)
#define EXP2(x) __builtin_amdgcn_exp2f(x)
#else
#define EXP2(x) exp2f(x)
#endif

__device__ __forceinline__ unsigned f2bf(float f) {  // f32 -> bf16 bits, RTNE
  unsigned u = __builtin_bit_cast(unsigned, f);
  return (u + 0x7FFFu + ((u >> 16) & 1u)) >> 16;
}

__device__ __forceinline__ unsigned cvtpk_bf16(float lo, float hi) {
  unsigned r;
  asm("v_cvt_pk_bf16_f32 %0, %1, %2" : "=v"(r) : "v"(lo), "v"(hi));
  return r;
}

__device__ __forceinline__ float sig_pre(float a) {  // 1/(1+2^a)
  return __builtin_amdgcn_rcpf(1.f + EXP2(a));
}

__global__ __launch_bounds__(NTHR, 2) void lstm_merged(
    const float* __restrict__ xg,
    const float* __restrict__ Wih0, const float* __restrict__ Whh0,
    const float* __restrict__ bih0, const float* __restrict__ bhh0,
    const float* __restrict__ Wih1, const float* __restrict__ Whh1,
    const float* __restrict__ bih1, const float* __restrict__ bhh1,
    const float* __restrict__ Wd,   const float* __restrict__ bd,
    float* __restrict__ out)
{
  __shared__ char lds[LDS_SZ];
  const int tid = threadIdx.x;
  const int l  = tid & 63;
  const int w  = tid >> 6;   // wave 0..7
  const int lg = l >> 4;     // lane k-group 0..3
  const int lr = l & 15;     // A: row-in-tile ; B/D: batch column
  const int b0 = blockIdx.x * 16;
  const bool early = (w < 4);  // phase order group (SIMD i hosts waves i, i+4)

  // ---- zero h/x state region (LH0..LX end = 18432 B) ----
  for (int i = tid; i < 18432 / 4; i += NTHR) ((int*)(lds + LH0))[i] = 0;
  // ---- stage Wih1 -> LDS frag image (pre-scaled bf16), coalesced [R9-verified] ----
  {
    const float4* Wv = (const float4*)Wih1;   // 16384 float4s
    #pragma unroll 4
    for (int i = 0; i < 32; ++i) {
      const int idx = i * 512 + tid;          // float4 index
      const float4 f = Wv[idx];
      const int e0 = idx * 4;                 // element index
      const int n = e0 >> 7, k = e0 & 127;    // row 0..511, col (mult of 4)
      const int tau = n >> 4;
      const float s = ((tau >> 3) == 2) ? (2.f * L2E) : (-L2E);
      const int lane = ((k >> 3) & 3) * 16 + (n & 15);
      const int byte = ((tau * 4 + (k >> 5)) * 64 + lane) * 16 + (k & 7) * 2;
      const unsigned lo = cvtpk_bf16(f.x * s, f.y * s);
      const unsigned hi = cvtpk_bf16(f.z * s, f.w * s);
      *(ull*)(lds + LW1 + byte) = ((ull)hi << 32) | lo;   // 8B, 8-aligned
    }
  }
  __syncthreads();
  // const-1.0 column at k==12 of both X buffers (pairs with L0 bias column)
  if (tid < 32) {
    const int buf = tid >> 4, b = tid & 15;
    *(unsigned short*)(lds + LX + buf * 1024 + 256 + b * 16 + 8) = 0x3F80;
  }

  // ---- weight registers: A0 (Whh0 + x/bias kfrag), A1h (Whh1), b1r (L1 bias) ----
  bf16x8 A0[4][5];
  bf16x8 A1h[4][4];
  f32x4 b1r[4];
  #pragma unroll
  for (int q = 0; q < 4; ++q) {
    const int n = (q * 8 + w) * 16 + lr;         // global gate row
    const float s = (q == 2) ? (2.f * L2E) : (-L2E);
    #pragma unroll
    for (int kf = 0; kf < 4; ++kf) {
      const float* s0 = &Whh0[n * H + kf * 32 + lg * 8];
      const float* s1 = &Whh1[n * H + kf * 32 + lg * 8];
      #pragma unroll
      for (int j = 0; j < 8; ++j) {
        A0[q][kf][j]  = (short)f2bf(s0[j] * s);
        A1h[q][kf][j] = (short)f2bf(s1[j] * s);
      }
    }
    #pragma unroll
    for (int j = 0; j < 8; ++j) {
      const int k = lg * 8 + j;
      float v = 0.f;
      if (k < CIN) v = Wih0[n * CIN + k] * s;
      else if (k == CIN) v = (bih0[n] + bhh0[n]) * s;  // pairs with 1.0 in X
      A0[q][4][j] = (short)f2bf(v);
    }
    #pragma unroll
    for (int r = 0; r < 4; ++r) {
      const int nd = (q * 8 + w) * 16 + lg * 4 + r;   // D-frag row for this lane
      b1r[q][r] = (bih1[nd] + bhh1[nd]) * s;
    }
  }
  const f32x4 zed = {0.f, 0.f, 0.f, 0.f};

  // per-lane geometry
  const int rdB  = lg * 256 + lr * 16;                       // B-frag read base
  const int bcol = w * 16 + lg * 4;                          // base h-column
  const int wrH  = (bcol >> 3) * 256 + lr * 16 + (bcol & 7) * 2;
  const int xb = tid & 15, xc = tid >> 4;                    // x loader (tid<192)
  const int wrX = (xc >> 3) * 256 + xb * 16 + (xc & 7) * 2;
  const size_t xbase = (size_t)(b0 + xb) * (CIN * T) + (size_t)xc * T;

  if (tid < 192)
    *(unsigned short*)(lds + LX + wrX) = (unsigned short)f2bf(xg[xbase]);
  __syncthreads();

  float c0v[4] = {0.f, 0.f, 0.f, 0.f};
  float c1v[4] = {0.f, 0.f, 0.f, 0.f};
  float h1v[4] = {0.f, 0.f, 0.f, 0.f};

  // ---- phase lambdas (per-wave work identical; only ORDER differs) ----
  auto ph_accA = [&](const bf16x8 bfH0[4], const bf16x8& bfX, f32x4 accA[4]) {
    #pragma unroll
    for (int q = 0; q < 4; ++q)
      accA[q] = __builtin_amdgcn_mfma_f32_16x16x32_bf16(A0[q][4], bfX, zed, 0, 0, 0);
    #pragma unroll
    for (int kf = 0; kf < 4; ++kf)
      #pragma unroll
      for (int q = 0; q < 4; ++q)
        accA[q] = __builtin_amdgcn_mfma_f32_16x16x32_bf16(A0[q][kf], bfH0[kf], accA[q], 0, 0, 0);
  };
  auto ph_ewL0 = [&](const f32x4 accA[4], int p) {
    float h0t[4];
    #pragma unroll
    for (int r = 0; r < 4; ++r) {
      const float iv = sig_pre(accA[0][r]);
      const float fv = sig_pre(accA[1][r]);
      const float gv = fmaf(-2.f, sig_pre(accA[2][r]), 1.f);
      const float ov = sig_pre(accA[3][r]);
      const float c  = fmaf(fv, c0v[r], iv * gv);
      c0v[r] = c;
      const float th = fmaf(-2.f, sig_pre(c * (2.f * L2E)), 1.f);
      h0t[r] = ov * th;
    }
    const unsigned hp0 = cvtpk_bf16(h0t[0], h0t[1]);
    const unsigned hp1 = cvtpk_bf16(h0t[2], h0t[3]);
    *(ull*)(lds + LH0 + p * 4096 + wrH) = ((ull)hp1 << 32) | hp0;
  };
  auto ph_accB = [&](const bf16x8 bfH0[4], const bf16x8 bfH1[4], f32x4 accB[4]) {
    #pragma unroll
    for (int q = 0; q < 4; ++q) accB[q] = b1r[q];
    #pragma unroll
    for (int kf = 0; kf < 4; ++kf) {
      bf16x8 af[4];                                          // Wih1 frags from LDS
      #pragma unroll
      for (int q = 0; q < 4; ++q)
        af[q] = *(const bf16x8*)(lds + LW1 + ((q * 8 + w) * 4 + kf) * 1024 + l * 16);
      #pragma unroll
      for (int q = 0; q < 4; ++q) {
        accB[q] = __builtin_amdgcn_mfma_f32_16x16x32_bf16(A1h[q][kf], bfH1[kf], accB[q], 0, 0, 0);
        accB[q] = __builtin_amdgcn_mfma_f32_16x16x32_bf16(af[q],      bfH0[kf], accB[q], 0, 0, 0);
      }
    }
  };
  auto ph_ewL1 = [&](const f32x4 accB[4], int p) {
    #pragma unroll
    for (int r = 0; r < 4; ++r) {
      const float iv = sig_pre(accB[0][r]);
      const float fv = sig_pre(accB[1][r]);
      const float gv = fmaf(-2.f, sig_pre(accB[2][r]), 1.f);
      const float ov = sig_pre(accB[3][r]);
      const float c  = fmaf(fv, c1v[r], iv * gv);
      c1v[r] = c;
      const float th = fmaf(-2.f, sig_pre(c * (2.f * L2E)), 1.f);
      h1v[r] = ov * th;
    }
    const unsigned hp0 = cvtpk_bf16(h1v[0], h1v[1]);
    const unsigned hp1 = cvtpk_bf16(h1v[2], h1v[3]);
    *(ull*)(lds + LH1 + (1 - p) * 4096 + wrH) = ((ull)hp1 << 32) | hp0;
  };

  // Iter t: L0(t) (h0(t-1), x(t)) and L1(t-1) (h1(t-2), h0(t-1)).
  // read H0[1-p], H1[p], X[p]; write H0[p], H1[1-p], X[1-p]. One barrier.
  #pragma unroll 2
  for (int t = 0; t < T; ++t) {
    const int p = t & 1;
    float xnext = 0.f;
    if (tid < 192) xnext = xg[xbase + (t + 1 < T ? t + 1 : t)];

    bf16x8 bfH0[4], bfH1[4], bfX;
    #pragma unroll
    for (int kf = 0; kf < 4; ++kf) {
      bfH0[kf] = *(const bf16x8*)(lds + LH0 + (1 - p) * 4096 + kf * 1024 + rdB);
      bfH1[kf] = *(const bf16x8*)(lds + LH1 + p * 4096 + kf * 1024 + rdB);
    }
    bfX = *(const bf16x8*)(lds + LX + p * 1024 + rdB);

    f32x4 accA[4], accB[4];
    if (early) {
      ph_accA(bfH0, bfX, accA);
      ph_ewL0(accA, p);
      ph_accB(bfH0, bfH1, accB);
      if (t > 0) ph_ewL1(accB, p);
    } else {
      ph_accB(bfH0, bfH1, accB);
      if (t > 0) ph_ewL1(accB, p);
      ph_accA(bfH0, bfX, accA);
      ph_ewL0(accA, p);
    }

    if (tid < 192) {
      *(unsigned short*)(lds + LX + (1 - p) * 1024 + wrX) =
          (unsigned short)cvtpk_bf16(xnext, xnext);
    }
    __syncthreads();
  }

  // ---- peeled final L1 step: h1(T-1) <- h1(T-2), h0(T-1) ----
  // T even: h0(T-1) in H0[1], h1(T-2) in H1[0].
  {
    bf16x8 bfH0[4], bfH1[4];
    #pragma unroll
    for (int kf = 0; kf < 4; ++kf) {
      bfH0[kf] = *(const bf16x8*)(lds + LH0 + 4096 + kf * 1024 + rdB);
      bfH1[kf] = *(const bf16x8*)(lds + LH1 + kf * 1024 + rdB);
    }
    f32x4 accB[4];
    ph_accB(bfH0, bfH1, accB);
    #pragma unroll
    for (int r = 0; r < 4; ++r) {
      const float iv = sig_pre(accB[0][r]);
      const float fv = sig_pre(accB[1][r]);
      const float gv = fmaf(-2.f, sig_pre(accB[2][r]), 1.f);
      const float ov = sig_pre(accB[3][r]);
      const float c  = fmaf(fv, c1v[r], iv * gv);
      c1v[r] = c;
      const float th = fmaf(-2.f, sig_pre(c * (2.f * L2E)), 1.f);
      h1v[r] = ov * th;
    }
  }

  // ---- epilogue: feats = h1(T-1), scores = sigmoid(h1 . Wd + bd) ----
  const float4 wd = *(const float4*)&Wd[bcol];
  const float partial = h1v[0] * wd.x + h1v[1] * wd.y + h1v[2] * wd.z + h1v[3] * wd.w;
  #pragma unroll
  for (int r = 0; r < 4; ++r)
    out[256 + (size_t)(b0 + lr) * H + (bcol + r)] = h1v[r];
  ((float*)(lds + LRED))[tid] = partial;
  __syncthreads();
  if (tid < 16) {
    float s = 0.f;
    #pragma unroll 8
    for (int k = 0; k < 32; ++k) s += ((float*)(lds + LRED))[tid + 16 * k];
    const float v = s + bd[0];
    out[b0 + tid] = __builtin_amdgcn_rcpf(1.f + EXP2(-v * L2E));
  }
}

extern "C" void kernel_launch(void* const* d_in, const int* in_sizes, int n_in,
                              void* d_out, int out_size, void* d_ws, size_t ws_size,
                              hipStream_t stream) {
  const float* x    = (const float*)d_in[0];
  // d_in[1] = seq_lengths : unused by the reference
  const float* Wih0 = (const float*)d_in[2];
  const float* Whh0 = (const float*)d_in[3];
  const float* bih0 = (const float*)d_in[4];
  const float* bhh0 = (const float*)d_in[5];
  const float* Wih1 = (const float*)d_in[6];
  const float* Whh1 = (const float*)d_in[7];
  const float* bih1 = (const float*)d_in[8];
  const float* bhh1 = (const float*)d_in[9];
  const float* Wd   = (const float*)d_in[10];
  const float* bd   = (const float*)d_in[11];
  (void)in_sizes; (void)n_in; (void)out_size; (void)d_ws; (void)ws_size;

  lstm_merged<<<dim3(16), dim3(NTHR), 0, stream>>>(
      x, Wih0, Whh0, bih0, bhh0, Wih1, Whh1, bih1, bhh1, Wd, bd, (float*)d_out);
}